// Round 1
// baseline (734.185 us; speedup 1.0000x reference)
//
#include <hip/hip_runtime.h>
#include <math.h>

#define NEGF (-1e30f)

// ---------------------------------------------------------------------------
// Kernel 1: Out[M x 512] = In[M x 256] @ W[256 x 512] (+ optional bias[512])
// block: 256 threads, 16 rows per block.
// ---------------------------------------------------------------------------
__global__ __launch_bounds__(256) void k_rowgemm(const float* __restrict__ In,
                                                 const float* __restrict__ W,
                                                 const float* __restrict__ bias,
                                                 float* __restrict__ Out, int M) {
    __shared__ float sIn[16 * 256];
    const int row0 = blockIdx.x * 16;
    const int tid = threadIdx.x;
    const int base = row0 * 256;
    const int limit = M * 256;
#pragma unroll
    for (int i = 0; i < 16; ++i) {
        int idx = tid + i * 256;
        int gidx = base + idx;
        sIn[idx] = (gidx < limit) ? In[gidx] : 0.f;
    }
    __syncthreads();
    float acc0[16], acc1[16];
#pragma unroll
    for (int r = 0; r < 16; ++r) { acc0[r] = 0.f; acc1[r] = 0.f; }
    const float* Wc0 = W + tid;
    const float* Wc1 = W + tid + 256;
    for (int e = 0; e < 256; ++e) {
        float w0 = Wc0[e * 512];
        float w1 = Wc1[e * 512];
#pragma unroll
        for (int r = 0; r < 16; ++r) {
            float a = sIn[r * 256 + e];   // broadcast, conflict-free
            acc0[r] = fmaf(a, w0, acc0[r]);
            acc1[r] = fmaf(a, w1, acc1[r]);
        }
    }
    float b0 = bias ? bias[tid] : 0.f;
    float b1 = bias ? bias[tid + 256] : 0.f;
#pragma unroll
    for (int r = 0; r < 16; ++r) {
        int row = row0 + r;
        if (row < M) {
            Out[row * 512 + tid] = acc0[r] + b0;
            Out[row * 512 + tid + 256] = acc1[r] + b1;
        }
    }
}

// ---------------------------------------------------------------------------
// Kernel 2: WpT[v][k] = Wp[k][v]   (Wp is 512 x 28)
// ---------------------------------------------------------------------------
__global__ void k_wpT(const float* __restrict__ Wp, float* __restrict__ WpT) {
    int i = blockIdx.x * 256 + threadIdx.x;
    if (i < 512 * 28) {
        int k = i / 28, v = i % 28;
        WpT[v * 512 + k] = Wp[i];
    }
}

__device__ __forceinline__ float tanh_fast(float x) {
    // tanh(x) = 1 - 2/(exp(2x)+1), exp via exp2
    float e2 = __builtin_amdgcn_exp2f(x * 2.885390081777927f); // 2*log2(e)
    return fmaf(-2.f, __builtin_amdgcn_rcpf(e2 + 1.f), 1.f);
}

// ---------------------------------------------------------------------------
// Kernel 3: per-cell blank/label log-probs.
// grid (7 t-tiles, 16 u-groups, 8 b), block (64, 4): wave = one u, lane = t.
// ---------------------------------------------------------------------------
__global__ __launch_bounds__(256) void k_cells(const float* __restrict__ f,
                                               const float* __restrict__ g,
                                               const float* __restrict__ WpT,
                                               const float* __restrict__ bp,
                                               const int* __restrict__ targets,
                                               const int* __restrict__ ilen,
                                               float* __restrict__ blank,
                                               float* __restrict__ lab) {
    const int b = blockIdx.z;
    const int t0 = blockIdx.x * 64;
    const int tlen = ilen[b];
    if (t0 >= tlen) return;                       // uniform: whole block exits
    const int u_raw = blockIdx.y * 4 + threadIdx.y;
    const int u = __builtin_amdgcn_readfirstlane(min(u_raw, 60));
    const int lane = threadIdx.x;
    const int t = t0 + lane;
    const int tid = threadIdx.y * 64 + lane;

    __shared__ float fs[64][33];                  // +1 pad: conflict-free

    float acc[28];
#pragma unroll
    for (int v = 0; v < 28; ++v) acc[v] = 0.f;

    const float* gu = g + (size_t)(b * 61 + u) * 512;
    const float* frow_base = f + (size_t)(b * 400) * 512;

    for (int kc = 0; kc < 512; kc += 32) {
        __syncthreads();
        {   // stage 64 t-rows x 32 k: 8 floats per thread (2x float4)
            int r = tid >> 2;                     // 0..63
            int c0 = (tid & 3) * 8;               // 0,8,16,24
            int tr = min(t0 + r, 399);
            const float4* src = (const float4*)(frow_base + (size_t)tr * 512 + kc + c0);
            float4 a0 = src[0];
            float4 a1 = src[1];
            fs[r][c0 + 0] = a0.x; fs[r][c0 + 1] = a0.y;
            fs[r][c0 + 2] = a0.z; fs[r][c0 + 3] = a0.w;
            fs[r][c0 + 4] = a1.x; fs[r][c0 + 5] = a1.y;
            fs[r][c0 + 6] = a1.z; fs[r][c0 + 7] = a1.w;
        }
        __syncthreads();

        float h[32];
#pragma unroll
        for (int j = 0; j < 32; ++j) {
            h[j] = tanh_fast(fs[lane][j] + gu[kc + j]);   // gu: scalar loads
        }
#pragma unroll
        for (int v = 0; v < 28; ++v) {
            const float* wr = WpT + v * 512 + kc;          // scalar loads
#pragma unroll
            for (int j = 0; j < 32; ++j) acc[v] = fmaf(h[j], wr[j], acc[v]);
        }
    }

    // epilogue: + bp, log-softmax denominator, select blank & label
    float m = -INFINITY;
#pragma unroll
    for (int v = 0; v < 28; ++v) { acc[v] += bp[v]; m = fmaxf(m, acc[v]); }
    float s = 0.f;
#pragma unroll
    for (int v = 0; v < 28; ++v)
        s += __builtin_amdgcn_exp2f((acc[v] - m) * 1.4426950408889634f);
    float lse = m + __logf(s);

    int tv = targets[b * 60 + min(u, 59)];        // in [0,26]
    float labv = 0.f;
#pragma unroll
    for (int v = 0; v < 27; ++v) if (v == tv) labv = acc[v];

    if (t < tlen && u_raw <= 60) {
        int cell = (b * 400 + t) * 61 + u;
        blank[cell] = acc[27] - lse;
        if (u <= 59) lab[cell] = labv - lse;
    }
}

// ---------------------------------------------------------------------------
// Kernel 4: anti-diagonal alpha recursion, one wave per batch.
// lane u holds alpha[d-u][u] after diagonal d.
// ---------------------------------------------------------------------------
__global__ __launch_bounds__(64) void k_alpha(const float* __restrict__ blank,
                                              const float* __restrict__ lab,
                                              const int* __restrict__ ilen,
                                              const int* __restrict__ ulenp,
                                              float* __restrict__ out) {
    const int b = blockIdx.x;
    const int u = threadIdx.x;
    const float* Bp = blank + (size_t)b * 400 * 61;
    const float* Lp = lab + (size_t)b * 400 * 61;
    const int tl = ilen[b];
    const int ul = ulenp[b];
    const int dstar = tl - 1 + ul;

    float cur = (u == 0) ? 0.f : NEGF;

    float pb[4], pl[4];
#pragma unroll
    for (int i = 0; i < 4; ++i) {
        int d = 1 + i;
        int t = d - u;
        pb[i] = (t >= 1 && t <= 399 && u <= 60) ? Bp[(t - 1) * 61 + u] : NEGF;
        pl[i] = (u >= 1 && u <= 60 && t >= 0 && t <= 399) ? Lp[t * 61 + (u - 1)] : NEGF;
    }

    for (int d0 = 1; d0 <= dstar; d0 += 4) {
#pragma unroll
        for (int i = 0; i < 4; ++i) {
            int d = d0 + i;
            if (d <= dstar) {
                float bv = pb[i], lv = pl[i];
                {   // prefetch d+4 (depth-4 pipeline)
                    int dn = d + 4;
                    if (dn <= dstar) {
                        int tn = dn - u;
                        pb[i] = (tn >= 1 && tn <= 399 && u <= 60) ? Bp[(tn - 1) * 61 + u] : NEGF;
                        pl[i] = (u >= 1 && u <= 60 && tn >= 0 && tn <= 399) ? Lp[tn * 61 + (u - 1)] : NEGF;
                    }
                }
                float up = __shfl_up(cur, 1, 64);
                float a = cur + bv;          // from below
                float c2 = up + lv;          // from left
                float mx = fmaxf(a, c2), mn = fminf(a, c2);
                float nv = mx + __logf(1.f + __builtin_amdgcn_exp2f((mn - mx) * 1.4426950408889634f));
                int t = d - u;
                bool valid = (t >= 0 && t <= 399 && u <= 60);
                cur = valid ? nv : cur;
                if (d == dstar && u == ul) {
                    out[b] = -(cur + Bp[(tl - 1) * 61 + ul]);
                }
            }
        }
    }
}

// ---------------------------------------------------------------------------
extern "C" void kernel_launch(void* const* d_in, const int* in_sizes, int n_in,
                              void* d_out, int out_size, void* d_ws, size_t ws_size,
                              hipStream_t stream) {
    const float* enc = (const float*)d_in[0];   // 8*400*256
    const float* dec = (const float*)d_in[1];   // 8*61*256
    const float* We  = (const float*)d_in[2];   // 256*512
    const float* Wd  = (const float*)d_in[3];   // 256*512
    const float* bf  = (const float*)d_in[4];   // 512
    const float* Wp  = (const float*)d_in[5];   // 512*28
    const float* bp  = (const float*)d_in[6];   // 28
    const int* targets = (const int*)d_in[7];   // 8*60
    const int* ilen    = (const int*)d_in[8];   // 8
    const int* ulen    = (const int*)d_in[9];   // 8
    float* out = (float*)d_out;                 // 8
    float* ws = (float*)d_ws;

    float* f     = ws;                 // 1,638,400
    float* g     = ws + 1638400;       // 249,856
    float* wpT   = ws + 1888256;       // 14,336
    float* blank = ws + 1902592;       // 195,200
    float* lab   = ws + 2097792;       // 195,200  (total ~9.2 MB)

    k_rowgemm<<<200, 256, 0, stream>>>(enc, We, nullptr, f, 3200);
    k_rowgemm<<<31, 256, 0, stream>>>(dec, Wd, bf, g, 488);
    k_wpT<<<56, 256, 0, stream>>>(Wp, wpT);

    dim3 gridC(7, 16, 8);
    dim3 blockC(64, 4, 1);
    k_cells<<<gridC, blockC, 0, stream>>>(f, g, wpT, bp, targets, ilen, blank, lab);

    k_alpha<<<8, 64, 0, stream>>>(blank, lab, ilen, ulen, out);
}

// Round 2
// 324.171 us; speedup vs baseline: 2.2648x; 2.2648x over previous
//
#include <hip/hip_runtime.h>
#include <hip/hip_bf16.h>
#include <math.h>

#define NEGF (-1e30f)
#define LOG2E 1.4426950408889634f
#define LN2 0.6931471805599453f

typedef __attribute__((ext_vector_type(8))) short bf16x8;
typedef __attribute__((ext_vector_type(4))) float f32x4;

__device__ __forceinline__ float tanh_fast(float x) {
    // tanh(x) = 1 - 2/(exp(2x)+1)
    float e2 = __builtin_amdgcn_exp2f(x * 2.885390081777927f); // 2*log2(e)
    return fmaf(-2.f, __builtin_amdgcn_rcpf(e2 + 1.f), 1.f);
}

__device__ __forceinline__ unsigned short f2bf(float x) {
    __hip_bfloat16 h = __float2bfloat16(x);   // gfx950: v_cvt_pk_bf16_f32 path
    return *reinterpret_cast<unsigned short*>(&h);
}

// ---------------------------------------------------------------------------
// Kernel 1 (fused prep): blocks 0..199 -> f = enc@We ; blocks 200..230 ->
// g = dec@Wd + bf ; block 231 -> Bfrag pack of Wp (bf16, MFMA B-lane order).
// ---------------------------------------------------------------------------
__global__ __launch_bounds__(256) void k_prep(const float* __restrict__ enc,
                                              const float* __restrict__ dec,
                                              const float* __restrict__ We,
                                              const float* __restrict__ Wd,
                                              const float* __restrict__ bfv,
                                              const float* __restrict__ Wp,
                                              float* __restrict__ f,
                                              float* __restrict__ g,
                                              unsigned short* __restrict__ Bfrag) {
    const int bid = blockIdx.x;
    const int tid = threadIdx.x;

    if (bid == 231) {
        // Bfrag[s*8 + j], s = c*128 + half*64 + lane:
        //   B[k][n] with n = half*16 + (lane&15), k = c*32 + (lane>>4)*8 + j
        for (int s = tid; s < 2048; s += 256) {
            int lane = s & 63;
            int half = (s >> 6) & 1;
            int c = s >> 7;
            int n = half * 16 + (lane & 15);
            int kbase = c * 32 + (lane >> 4) * 8;
            unsigned short* dst = Bfrag + (size_t)s * 8;
#pragma unroll
            for (int j = 0; j < 8; ++j) {
                float v = (n < 28) ? Wp[(kbase + j) * 28 + n] : 0.f;
                dst[j] = f2bf(v);
            }
        }
        return;
    }

    const float* In; const float* W; const float* bias; float* Out; int M, row0;
    if (bid < 200) { In = enc; W = We;  bias = nullptr; Out = f; M = 3200; row0 = bid * 16; }
    else           { In = dec; W = Wd;  bias = bfv;     Out = g; M = 488;  row0 = (bid - 200) * 16; }

    __shared__ float sIn[16 * 256];
    {
        int base = row0 * 256, limit = M * 256;
#pragma unroll
        for (int i = 0; i < 16; ++i) {
            int idx = tid + i * 256;
            int gidx = base + idx;
            sIn[idx] = (gidx < limit) ? In[gidx] : 0.f;
        }
    }
    __syncthreads();

    float acc0[16], acc1[16];
#pragma unroll
    for (int r = 0; r < 16; ++r) { acc0[r] = 0.f; acc1[r] = 0.f; }

    const float* wp = W + 2 * tid;    // this thread owns cols 2*tid, 2*tid+1
    float2 wb[4];
#pragma unroll
    for (int i = 0; i < 4; ++i) wb[i] = *(const float2*)(wp + i * 512);

    for (int e0 = 0; e0 < 256; e0 += 4) {
        float2 wn[4];
        if (e0 + 4 < 256) {
#pragma unroll
            for (int i = 0; i < 4; ++i) wn[i] = *(const float2*)(wp + (e0 + 4 + i) * 512);
        }
#pragma unroll
        for (int r = 0; r < 16; ++r) {
            float4 a = *(const float4*)&sIn[r * 256 + e0];   // wave-uniform: LDS broadcast
            acc0[r] = fmaf(a.x, wb[0].x, acc0[r]); acc1[r] = fmaf(a.x, wb[0].y, acc1[r]);
            acc0[r] = fmaf(a.y, wb[1].x, acc0[r]); acc1[r] = fmaf(a.y, wb[1].y, acc1[r]);
            acc0[r] = fmaf(a.z, wb[2].x, acc0[r]); acc1[r] = fmaf(a.z, wb[2].y, acc1[r]);
            acc0[r] = fmaf(a.w, wb[3].x, acc0[r]); acc1[r] = fmaf(a.w, wb[3].y, acc1[r]);
        }
        if (e0 + 4 < 256) {
#pragma unroll
            for (int i = 0; i < 4; ++i) wb[i] = wn[i];
        }
    }

    float b0 = bias ? bias[2 * tid] : 0.f;
    float b1 = bias ? bias[2 * tid + 1] : 0.f;
#pragma unroll
    for (int r = 0; r < 16; ++r) {
        int row = row0 + r;
        if (row < M) {
            float2 o; o.x = acc0[r] + b0; o.y = acc1[r] + b1;
            *(float2*)&Out[(size_t)row * 512 + 2 * tid] = o;
        }
    }
}

// ---------------------------------------------------------------------------
// Kernel 2: per-cell blank/label log-probs via bf16 MFMA.
// grid (25 t-tiles, 16 u-groups, 8 b), block (64,4): wave = one u, 16 t-rows.
// ---------------------------------------------------------------------------
__global__ __launch_bounds__(256) void k_cells(const float* __restrict__ f,
                                               const float* __restrict__ g,
                                               const unsigned short* __restrict__ Bfrag,
                                               const float* __restrict__ bp,
                                               const int* __restrict__ targets,
                                               const int* __restrict__ ilen,
                                               float* __restrict__ blank,
                                               float* __restrict__ lab) {
    const int b = blockIdx.z;
    const int tlen = ilen[b];
    const int t0 = blockIdx.x * 16;
    if (t0 >= tlen) return;                       // block-uniform exit
    const int wave = threadIdx.y;
    const int lane = threadIdx.x;
    const int u_raw = blockIdx.y * 4 + wave;
    const int u = min(u_raw, 60);
    const int tid = wave * 64 + lane;

    __shared__ float fs[16 * 516];                // stride 516: 2-way bank alias (free)

    {   // stage f tile (16 rows x 512), coalesced float4, conflict-free writes
        const float4* src = (const float4*)(f + (size_t)(b * 400 + t0) * 512);
#pragma unroll
        for (int i = 0; i < 8; ++i) {
            int idx = tid + i * 256;              // float4 id, 0..2047
            int row = idx >> 7;
            int c4 = idx & 127;
            float4 v = src[idx];
            *(float4*)&fs[row * 516 + c4 * 4] = v;
        }
    }
    __syncthreads();

    const int quad = lane >> 4;
    const int m16 = lane & 15;
    const float* gu = g + (size_t)(b * 61 + u) * 512 + quad * 8;
    const float* fsrow = fs + m16 * 516 + quad * 8;
    f32x4 acc0 = {0.f, 0.f, 0.f, 0.f};
    f32x4 acc1 = {0.f, 0.f, 0.f, 0.f};

#pragma unroll 4
    for (int c = 0; c < 16; ++c) {
        float4 fa = *(const float4*)(fsrow + c * 32);
        float4 fb = *(const float4*)(fsrow + c * 32 + 4);
        float4 ga = *(const float4*)(gu + c * 32);
        float4 gb = *(const float4*)(gu + c * 32 + 4);
        union { unsigned short s[8]; bf16x8 v; } A;
        A.s[0] = f2bf(tanh_fast(fa.x + ga.x));
        A.s[1] = f2bf(tanh_fast(fa.y + ga.y));
        A.s[2] = f2bf(tanh_fast(fa.z + ga.z));
        A.s[3] = f2bf(tanh_fast(fa.w + ga.w));
        A.s[4] = f2bf(tanh_fast(fb.x + gb.x));
        A.s[5] = f2bf(tanh_fast(fb.y + gb.y));
        A.s[6] = f2bf(tanh_fast(fb.z + gb.z));
        A.s[7] = f2bf(tanh_fast(fb.w + gb.w));
        bf16x8 B0 = *(const bf16x8*)(Bfrag + ((size_t)(c * 2 + 0) * 64 + lane) * 8);
        bf16x8 B1 = *(const bf16x8*)(Bfrag + ((size_t)(c * 2 + 1) * 64 + lane) * 8);
        acc0 = __builtin_amdgcn_mfma_f32_16x16x32_bf16(A.v, B0, acc0, 0, 0, 0);
        acc1 = __builtin_amdgcn_mfma_f32_16x16x32_bf16(A.v, B1, acc1, 0, 0, 0);
    }

    // epilogue: D layout col n = lane&15, row m = quad*4 + reg
    float bp0 = bp[m16];
    int n1 = 16 + m16;
    bool n1v = (n1 < 28);
    float bp1 = n1v ? bp[n1] : 0.f;
    int tv = targets[b * 60 + min(u, 59)];

    float res_blank[4], res_lab[4];
#pragma unroll
    for (int r = 0; r < 4; ++r) {
        float l0 = acc0[r] + bp0;
        float l1 = n1v ? (acc1[r] + bp1) : NEGF;
        float mx = fmaxf(l0, l1);
        mx = fmaxf(mx, __shfl_xor(mx, 1, 64));
        mx = fmaxf(mx, __shfl_xor(mx, 2, 64));
        mx = fmaxf(mx, __shfl_xor(mx, 4, 64));
        mx = fmaxf(mx, __shfl_xor(mx, 8, 64));
        float s = __builtin_amdgcn_exp2f((l0 - mx) * LOG2E) +
                  __builtin_amdgcn_exp2f((l1 - mx) * LOG2E);
        s += __shfl_xor(s, 1, 64);
        s += __shfl_xor(s, 2, 64);
        s += __shfl_xor(s, 4, 64);
        s += __shfl_xor(s, 8, 64);
        float lse = mx + __logf(s);
        int base = lane & 48;
        float labsrc = (tv < 16) ? l0 : l1;
        float labv = __shfl(labsrc, base | (tv & 15), 64);
        float blankv = __shfl(l1, base | 11, 64);   // v=27 -> half1 local 11
        res_blank[r] = blankv - lse;
        res_lab[r] = labv - lse;
    }

    if (m16 == 0 && u_raw <= 60) {
#pragma unroll
        for (int r = 0; r < 4; ++r) {
            int t = t0 + quad * 4 + r;
            if (t < tlen) {
                int cell = (b * 400 + t) * 61 + u;
                blank[cell] = res_blank[r];
                if (u <= 59) lab[cell] = res_lab[r];
            }
        }
    }
}

// ---------------------------------------------------------------------------
// Kernel 3: anti-diagonal alpha recursion, one wave per batch.
// DPP wave_shr:1 for the lane shift (2 cyc vs ~50 for ds_bpermute).
// ---------------------------------------------------------------------------
__device__ __forceinline__ float wave_shr1(float x) {
    int i = __builtin_bit_cast(int, x);
    int r = __builtin_amdgcn_update_dpp(0, i, 0x138, 0xf, 0xf, true); // wf_shr:1
    return __builtin_bit_cast(float, r);
}

__global__ __launch_bounds__(64) void k_alpha(const float* __restrict__ blank,
                                              const float* __restrict__ lab,
                                              const int* __restrict__ ilen,
                                              const int* __restrict__ ulenp,
                                              float* __restrict__ out) {
    const int b = blockIdx.x;
    const int u = threadIdx.x;
    const float* Bp = blank + (size_t)b * 400 * 61;
    const float* Lp = lab + (size_t)b * 400 * 61;
    const int tl = ilen[b];
    const int ul = ulenp[b];
    const int dstar = tl - 1 + ul;
    const bool uok = (u <= 60);
    const bool lok = (u >= 1 && u <= 60);

    float cur = (u == 0) ? 0.f : NEGF;

    float pb[8], pl[8];
#pragma unroll
    for (int i = 0; i < 8; ++i) {
        int d = 1 + i, t = d - u;
        pb[i] = (t >= 1 && t <= 399 && uok) ? Bp[(t - 1) * 61 + u] : NEGF;
        pl[i] = (lok && t >= 0 && t <= 399) ? Lp[t * 61 + (u - 1)] : NEGF;
    }

    for (int d0 = 1; d0 <= dstar; d0 += 8) {
#pragma unroll
        for (int i = 0; i < 8; ++i) {
            int d = d0 + i;
            if (d <= dstar) {
                float bv = pb[i], lv = pl[i];
                {   // prefetch distance 8
                    int dn = d + 8;
                    if (dn <= dstar) {
                        int tn = dn - u;
                        pb[i] = (tn >= 1 && tn <= 399 && uok) ? Bp[(tn - 1) * 61 + u] : NEGF;
                        pl[i] = (lok && tn >= 0 && tn <= 399) ? Lp[tn * 61 + (u - 1)] : NEGF;
                    }
                }
                float up = wave_shr1(cur);
                float a = cur + bv;
                float c2 = up + lv;
                float mx = fmaxf(a, c2), mn = fminf(a, c2);
                float nv = mx + __logf(1.f + __builtin_amdgcn_exp2f((mn - mx) * LOG2E));
                int t = d - u;
                bool valid = (t >= 0 && t <= 399 && uok);
                cur = valid ? nv : cur;
                if (d == dstar && u == ul) {
                    out[b] = -(cur + Bp[(tl - 1) * 61 + ul]);
                }
            }
        }
    }
}

// ---------------------------------------------------------------------------
extern "C" void kernel_launch(void* const* d_in, const int* in_sizes, int n_in,
                              void* d_out, int out_size, void* d_ws, size_t ws_size,
                              hipStream_t stream) {
    const float* enc = (const float*)d_in[0];   // 8*400*256
    const float* dec = (const float*)d_in[1];   // 8*61*256
    const float* We  = (const float*)d_in[2];   // 256*512
    const float* Wd  = (const float*)d_in[3];   // 256*512
    const float* bf  = (const float*)d_in[4];   // 512
    const float* Wp  = (const float*)d_in[5];   // 512*28
    const float* bp  = (const float*)d_in[6];   // 28
    const int* targets = (const int*)d_in[7];   // 8*60
    const int* ilen    = (const int*)d_in[8];   // 8
    const int* ulen    = (const int*)d_in[9];   // 8
    float* out = (float*)d_out;                 // 8
    float* ws = (float*)d_ws;

    float* f     = ws;                                   // 1,638,400 floats
    float* g     = ws + 1638400;                         //   249,856 floats
    unsigned short* Bfrag = (unsigned short*)(ws + 1888256); // 16,384 u16 (8,192 floats)
    float* blank = ws + 1896448;                         //   195,200 floats
    float* lab   = ws + 2091648;                         //   195,200 floats

    k_prep<<<232, 256, 0, stream>>>(enc, dec, We, Wd, bf, Wp, f, g, Bfrag);

    dim3 gridC(25, 16, 8);
    dim3 blockC(64, 4, 1);
    k_cells<<<gridC, blockC, 0, stream>>>(f, g, Bfrag, bp, targets, ilen, blank, lab);

    k_alpha<<<8, 64, 0, stream>>>(blank, lab, ilen, ulen, out);
}

// Round 3
// 251.566 us; speedup vs baseline: 2.9185x; 1.2886x over previous
//
#include <hip/hip_runtime.h>
#include <hip/hip_bf16.h>
#include <math.h>

#define NEGF (-1e30f)
#define LOG2E 1.4426950408889634f

typedef __attribute__((ext_vector_type(8))) short bf16x8;
typedef __attribute__((ext_vector_type(4))) float f32x4;

#define DROWS 460            // diagonals 0..459 (t+u, t<=399, u<=60)
#define DPITCH 64            // lanes per diagonal row

__device__ __forceinline__ float tanh_fast(float x) {
    // tanh(x) = 1 - 2/(exp(2x)+1)
    float e2 = __builtin_amdgcn_exp2f(x * 2.885390081777927f); // 2*log2(e)
    return fmaf(-2.f, __builtin_amdgcn_rcpf(e2 + 1.f), 1.f);
}

__device__ __forceinline__ unsigned short f2bf(float x) {
    __hip_bfloat16 h = __float2bfloat16(x);
    return *reinterpret_cast<unsigned short*>(&h);
}

__device__ __forceinline__ float wave_shr1(float x) {
    int i = __builtin_bit_cast(int, x);
    int r = __builtin_amdgcn_update_dpp(0, i, 0x138, 0xf, 0xf, true); // wf_shr:1
    return __builtin_bit_cast(float, r);
}

// ---------------------------------------------------------------------------
// Kernel 1 (fused prep): blocks 0..199 -> f = enc@We ; blocks 200..230 ->
// g = dec@Wd + bf ; block 231 -> Bfrag pack of Wp (bf16, MFMA B-lane order).
// ---------------------------------------------------------------------------
__global__ __launch_bounds__(256) void k_prep(const float* __restrict__ enc,
                                              const float* __restrict__ dec,
                                              const float* __restrict__ We,
                                              const float* __restrict__ Wd,
                                              const float* __restrict__ bfv,
                                              const float* __restrict__ Wp,
                                              float* __restrict__ f,
                                              float* __restrict__ g,
                                              unsigned short* __restrict__ Bfrag) {
    const int bid = blockIdx.x;
    const int tid = threadIdx.x;

    if (bid == 231) {
        // Bfrag[s*8 + j], s = c*128 + half*64 + lane:
        //   B[k][n] with n = half*16 + (lane&15), k = c*32 + (lane>>4)*8 + j
        for (int s = tid; s < 2048; s += 256) {
            int lane = s & 63;
            int half = (s >> 6) & 1;
            int c = s >> 7;
            int n = half * 16 + (lane & 15);
            int kbase = c * 32 + (lane >> 4) * 8;
            unsigned short* dst = Bfrag + (size_t)s * 8;
#pragma unroll
            for (int j = 0; j < 8; ++j) {
                float v = (n < 28) ? Wp[(kbase + j) * 28 + n] : 0.f;
                dst[j] = f2bf(v);
            }
        }
        return;
    }

    const float* In; const float* W; const float* bias; float* Out; int M, row0;
    if (bid < 200) { In = enc; W = We;  bias = nullptr; Out = f; M = 3200; row0 = bid * 16; }
    else           { In = dec; W = Wd;  bias = bfv;     Out = g; M = 488;  row0 = (bid - 200) * 16; }

    __shared__ float sIn[16 * 256];
    {
        int base = row0 * 256, limit = M * 256;
#pragma unroll
        for (int i = 0; i < 16; ++i) {
            int idx = tid + i * 256;
            int gidx = base + idx;
            sIn[idx] = (gidx < limit) ? In[gidx] : 0.f;
        }
    }
    __syncthreads();

    float acc0[16], acc1[16];
#pragma unroll
    for (int r = 0; r < 16; ++r) { acc0[r] = 0.f; acc1[r] = 0.f; }

    const float* wp = W + 2 * tid;    // this thread owns cols 2*tid, 2*tid+1
    float2 wb[4];
#pragma unroll
    for (int i = 0; i < 4; ++i) wb[i] = *(const float2*)(wp + i * 512);

    for (int e0 = 0; e0 < 256; e0 += 4) {
        float2 wn[4];
        if (e0 + 4 < 256) {
#pragma unroll
            for (int i = 0; i < 4; ++i) wn[i] = *(const float2*)(wp + (e0 + 4 + i) * 512);
        }
#pragma unroll
        for (int r = 0; r < 16; ++r) {
            float4 a = *(const float4*)&sIn[r * 256 + e0];   // wave-uniform: LDS broadcast
            acc0[r] = fmaf(a.x, wb[0].x, acc0[r]); acc1[r] = fmaf(a.x, wb[0].y, acc1[r]);
            acc0[r] = fmaf(a.y, wb[1].x, acc0[r]); acc1[r] = fmaf(a.y, wb[1].y, acc1[r]);
            acc0[r] = fmaf(a.z, wb[2].x, acc0[r]); acc1[r] = fmaf(a.z, wb[2].y, acc1[r]);
            acc0[r] = fmaf(a.w, wb[3].x, acc0[r]); acc1[r] = fmaf(a.w, wb[3].y, acc1[r]);
        }
        if (e0 + 4 < 256) {
#pragma unroll
            for (int i = 0; i < 4; ++i) wb[i] = wn[i];
        }
    }

    float b0 = bias ? bias[2 * tid] : 0.f;
    float b1 = bias ? bias[2 * tid + 1] : 0.f;
#pragma unroll
    for (int r = 0; r < 16; ++r) {
        int row = row0 + r;
        if (row < M) {
            float2 o; o.x = acc0[r] + b0; o.y = acc1[r] + b1;
            *(float2*)&Out[(size_t)row * 512 + 2 * tid] = o;
        }
    }
}

// ---------------------------------------------------------------------------
// Kernel 2: per-cell blank/label log-probs via bf16 MFMA.
// Output in DIAGONAL-MAJOR float2 {blank, lab} layout: pairD[b][t+u][u].
// grid (25 t-tiles, 16 u-groups, 8 b), block (64,4): wave = one u, 16 t-rows.
// ---------------------------------------------------------------------------
__global__ __launch_bounds__(256) void k_cells(const float* __restrict__ f,
                                               const float* __restrict__ g,
                                               const unsigned short* __restrict__ Bfrag,
                                               const float* __restrict__ bp,
                                               const int* __restrict__ targets,
                                               const int* __restrict__ ilen,
                                               float2* __restrict__ pairD) {
    const int b = blockIdx.z;
    const int tlen = ilen[b];
    const int t0 = blockIdx.x * 16;
    if (t0 >= tlen) return;                       // block-uniform exit
    const int wave = threadIdx.y;
    const int lane = threadIdx.x;
    const int u_raw = blockIdx.y * 4 + wave;
    const int u = min(u_raw, 60);
    const int tid = wave * 64 + lane;

    __shared__ float fs[16 * 516];                // stride 516: 2-way bank alias (free)

    {   // stage f tile (16 rows x 512), coalesced float4, conflict-free writes
        const float4* src = (const float4*)(f + (size_t)(b * 400 + t0) * 512);
#pragma unroll
        for (int i = 0; i < 8; ++i) {
            int idx = tid + i * 256;              // float4 id, 0..2047
            int row = idx >> 7;
            int c4 = idx & 127;
            float4 v = src[idx];
            *(float4*)&fs[row * 516 + c4 * 4] = v;
        }
    }
    __syncthreads();

    const int quad = lane >> 4;
    const int m16 = lane & 15;
    const float* gu = g + (size_t)(b * 61 + u) * 512 + quad * 8;
    const float* fsrow = fs + m16 * 516 + quad * 8;
    f32x4 acc0 = {0.f, 0.f, 0.f, 0.f};
    f32x4 acc1 = {0.f, 0.f, 0.f, 0.f};

#pragma unroll 4
    for (int c = 0; c < 16; ++c) {
        float4 fa = *(const float4*)(fsrow + c * 32);
        float4 fb = *(const float4*)(fsrow + c * 32 + 4);
        float4 ga = *(const float4*)(gu + c * 32);
        float4 gb = *(const float4*)(gu + c * 32 + 4);
        union { unsigned short s[8]; bf16x8 v; } A;
        A.s[0] = f2bf(tanh_fast(fa.x + ga.x));
        A.s[1] = f2bf(tanh_fast(fa.y + ga.y));
        A.s[2] = f2bf(tanh_fast(fa.z + ga.z));
        A.s[3] = f2bf(tanh_fast(fa.w + ga.w));
        A.s[4] = f2bf(tanh_fast(fb.x + gb.x));
        A.s[5] = f2bf(tanh_fast(fb.y + gb.y));
        A.s[6] = f2bf(tanh_fast(fb.z + gb.z));
        A.s[7] = f2bf(tanh_fast(fb.w + gb.w));
        bf16x8 B0 = *(const bf16x8*)(Bfrag + ((size_t)(c * 2 + 0) * 64 + lane) * 8);
        bf16x8 B1 = *(const bf16x8*)(Bfrag + ((size_t)(c * 2 + 1) * 64 + lane) * 8);
        acc0 = __builtin_amdgcn_mfma_f32_16x16x32_bf16(A.v, B0, acc0, 0, 0, 0);
        acc1 = __builtin_amdgcn_mfma_f32_16x16x32_bf16(A.v, B1, acc1, 0, 0, 0);
    }

    // epilogue: D layout col n = lane&15, row m = quad*4 + reg
    float bp0 = bp[m16];
    int n1 = 16 + m16;
    bool n1v = (n1 < 28);
    float bp1 = n1v ? bp[n1] : 0.f;
    int tv = targets[b * 60 + min(u, 59)];

    float res_blank[4], res_lab[4];
#pragma unroll
    for (int r = 0; r < 4; ++r) {
        float l0 = acc0[r] + bp0;
        float l1 = n1v ? (acc1[r] + bp1) : NEGF;
        float mx = fmaxf(l0, l1);
        mx = fmaxf(mx, __shfl_xor(mx, 1, 64));
        mx = fmaxf(mx, __shfl_xor(mx, 2, 64));
        mx = fmaxf(mx, __shfl_xor(mx, 4, 64));
        mx = fmaxf(mx, __shfl_xor(mx, 8, 64));
        float s = __builtin_amdgcn_exp2f((l0 - mx) * LOG2E) +
                  __builtin_amdgcn_exp2f((l1 - mx) * LOG2E);
        s += __shfl_xor(s, 1, 64);
        s += __shfl_xor(s, 2, 64);
        s += __shfl_xor(s, 4, 64);
        s += __shfl_xor(s, 8, 64);
        float lse = mx + __logf(s);
        int base = lane & 48;
        float labsrc = (tv < 16) ? l0 : l1;
        float labv = __shfl(labsrc, base | (tv & 15), 64);
        float blankv = __shfl(l1, base | 11, 64);   // v=27 -> half1 local 11
        res_blank[r] = blankv - lse;
        res_lab[r] = labv - lse;
    }

    if (m16 == 0 && u_raw <= 60) {
        float2* Pd = pairD + (size_t)b * (DROWS * DPITCH);
#pragma unroll
        for (int r = 0; r < 4; ++r) {
            int t = t0 + quad * 4 + r;
            if (t < tlen) {
                int d = t + u;
                float2 pr;
                pr.x = res_blank[r];
                pr.y = (u <= 59) ? res_lab[r] : NEGF;
                Pd[d * DPITCH + u] = pr;
            }
        }
    }
}

// ---------------------------------------------------------------------------
// Kernel 3: anti-diagonal alpha recursion, one wave per batch.
// Diagonal-major layout: step d reads ONE coalesced float2 row (d-1).
// lab[t][u-1] comes from lane u-1 via DPP wave_shr:1 (off critical path).
// ---------------------------------------------------------------------------
#define PF 16
__global__ __launch_bounds__(64) void k_alpha(const float2* __restrict__ pairD,
                                              const int* __restrict__ ilen,
                                              const int* __restrict__ ulenp,
                                              float* __restrict__ out) {
    const int b = blockIdx.x;
    const int u = threadIdx.x;
    const float2* Pd = pairD + (size_t)b * (DROWS * DPITCH);
    const int tl = ilen[b];
    const int ul = ulenp[b];
    const int dstar = tl - 1 + ul;
    const bool uok = (u <= 60);
    const bool lok = (u >= 1 && u <= 60);

    float cur = (u == 0) ? 0.f : NEGF;

    float2 pf[PF];                       // raw loads; selects applied at consume
#pragma unroll
    for (int i = 0; i < PF; ++i) pf[i] = Pd[i * DPITCH + u];   // rows 0..PF-1

    for (int d0 = 1; d0 <= dstar; d0 += PF) {
#pragma unroll
        for (int i = 0; i < PF; ++i) {
            int d = d0 + i;
            if (d <= dstar) {
                float2 v = pf[i];
                int dn = d + PF;
                if (dn <= dstar) pf[i] = Pd[(dn - 1) * DPITCH + u];  // prefetch
                int t = d - u;
                float bv = (t >= 1 && t <= 399 && uok) ? v.x : NEGF;
                float lvn = wave_shr1(v.y);            // lab[t][u-1] from lane u-1
                float lv = (lok && t >= 0 && t <= 399) ? lvn : NEGF;
                float up = wave_shr1(cur);
                float a = cur + bv;
                float c2 = up + lv;
                float mx = fmaxf(a, c2), mn = fminf(a, c2);
                float nv = mx + __logf(1.f + __builtin_amdgcn_exp2f((mn - mx) * LOG2E));
                bool valid = (t >= 0 && t <= 399 && uok);
                cur = valid ? nv : cur;
            }
        }
    }
    if (u == ul) out[b] = -(cur + Pd[dstar * DPITCH + ul].x);
}

// ---------------------------------------------------------------------------
extern "C" void kernel_launch(void* const* d_in, const int* in_sizes, int n_in,
                              void* d_out, int out_size, void* d_ws, size_t ws_size,
                              hipStream_t stream) {
    const float* enc = (const float*)d_in[0];   // 8*400*256
    const float* dec = (const float*)d_in[1];   // 8*61*256
    const float* We  = (const float*)d_in[2];   // 256*512
    const float* Wd  = (const float*)d_in[3];   // 256*512
    const float* bf  = (const float*)d_in[4];   // 512
    const float* Wp  = (const float*)d_in[5];   // 512*28
    const float* bp  = (const float*)d_in[6];   // 28
    const int* targets = (const int*)d_in[7];   // 8*60
    const int* ilen    = (const int*)d_in[8];   // 8
    const int* ulen    = (const int*)d_in[9];   // 8
    float* out = (float*)d_out;                 // 8
    float* ws = (float*)d_ws;

    float* f     = ws;                                       // 1,638,400 floats
    float* g     = ws + 1638400;                             //   249,856 floats
    unsigned short* Bfrag = (unsigned short*)(ws + 1888256); // 16,384 u16 (8,192 floats)
    float2* pairD = (float2*)(ws + 1896448);                 // 8*460*64 float2 = 471,040 floats

    k_prep<<<232, 256, 0, stream>>>(enc, dec, We, Wd, bf, Wp, f, g, Bfrag);

    dim3 gridC(25, 16, 8);
    dim3 blockC(64, 4, 1);
    k_cells<<<gridC, blockC, 0, stream>>>(f, g, Bfrag, bp, targets, ilen, pairD);

    k_alpha<<<8, 64, 0, stream>>>(pairD, ilen, ulen, out);
}

// Round 4
// 189.759 us; speedup vs baseline: 3.8690x; 1.3257x over previous
//
#include <hip/hip_runtime.h>
#include <hip/hip_bf16.h>
#include <math.h>

#define NEGF (-1e30f)
#define LOG2E 1.4426950408889634f

typedef __attribute__((ext_vector_type(8))) short bf16x8;
typedef __attribute__((ext_vector_type(4))) float f32x4;

#define DROWS_PAD 480        // diagonals 0..459 used; padded to 480 for static prefetch
#define DPITCH 64            // lanes per diagonal row
#define D_TRIP 464           // fixed trip count: 29 * 16, >= max dstar (459)
#define PF 16                // prefetch depth (rows)

__device__ __forceinline__ float tanh_fast(float x) {
    // tanh(x) = 1 - 2/(exp(2x)+1)
    float e2 = __builtin_amdgcn_exp2f(x * 2.885390081777927f); // 2*log2(e)
    return fmaf(-2.f, __builtin_amdgcn_rcpf(e2 + 1.f), 1.f);
}

__device__ __forceinline__ unsigned short f2bf(float x) {
    __hip_bfloat16 h = __float2bfloat16(x);
    return *reinterpret_cast<unsigned short*>(&h);
}

__device__ __forceinline__ float wave_shr1(float x) {
    int i = __builtin_bit_cast(int, x);
    int r = __builtin_amdgcn_update_dpp(0, i, 0x138, 0xf, 0xf, true); // wf_shr:1
    return __builtin_bit_cast(float, r);
}

// ---------------------------------------------------------------------------
// Kernel 1 (fused prep): blocks 0..199 -> f = enc@We ; blocks 200..230 ->
// g = dec@Wd + bf ; block 231 -> Bfrag pack of Wp (bf16, MFMA B-lane order).
// ---------------------------------------------------------------------------
__global__ __launch_bounds__(256) void k_prep(const float* __restrict__ enc,
                                              const float* __restrict__ dec,
                                              const float* __restrict__ We,
                                              const float* __restrict__ Wd,
                                              const float* __restrict__ bfv,
                                              const float* __restrict__ Wp,
                                              float* __restrict__ f,
                                              float* __restrict__ g,
                                              unsigned short* __restrict__ Bfrag) {
    const int bid = blockIdx.x;
    const int tid = threadIdx.x;

    if (bid == 231) {
        // Bfrag[s*8 + j], s = c*128 + half*64 + lane:
        //   B[k][n] with n = half*16 + (lane&15), k = c*32 + (lane>>4)*8 + j
        for (int s = tid; s < 2048; s += 256) {
            int lane = s & 63;
            int half = (s >> 6) & 1;
            int c = s >> 7;
            int n = half * 16 + (lane & 15);
            int kbase = c * 32 + (lane >> 4) * 8;
            unsigned short* dst = Bfrag + (size_t)s * 8;
#pragma unroll
            for (int j = 0; j < 8; ++j) {
                float v = (n < 28) ? Wp[(kbase + j) * 28 + n] : 0.f;
                dst[j] = f2bf(v);
            }
        }
        return;
    }

    const float* In; const float* W; const float* bias; float* Out; int M, row0;
    if (bid < 200) { In = enc; W = We;  bias = nullptr; Out = f; M = 3200; row0 = bid * 16; }
    else           { In = dec; W = Wd;  bias = bfv;     Out = g; M = 488;  row0 = (bid - 200) * 16; }

    __shared__ float sIn[16 * 256];
    {
        int base = row0 * 256, limit = M * 256;
#pragma unroll
        for (int i = 0; i < 16; ++i) {
            int idx = tid + i * 256;
            int gidx = base + idx;
            sIn[idx] = (gidx < limit) ? In[gidx] : 0.f;
        }
    }
    __syncthreads();

    float acc0[16], acc1[16];
#pragma unroll
    for (int r = 0; r < 16; ++r) { acc0[r] = 0.f; acc1[r] = 0.f; }

    const float* wp = W + 2 * tid;    // this thread owns cols 2*tid, 2*tid+1
    float2 wb[4];
#pragma unroll
    for (int i = 0; i < 4; ++i) wb[i] = *(const float2*)(wp + i * 512);

    for (int e0 = 0; e0 < 256; e0 += 4) {
        float2 wn[4];
        if (e0 + 4 < 256) {
#pragma unroll
            for (int i = 0; i < 4; ++i) wn[i] = *(const float2*)(wp + (e0 + 4 + i) * 512);
        }
#pragma unroll
        for (int r = 0; r < 16; ++r) {
            float4 a = *(const float4*)&sIn[r * 256 + e0];   // wave-uniform: LDS broadcast
            acc0[r] = fmaf(a.x, wb[0].x, acc0[r]); acc1[r] = fmaf(a.x, wb[0].y, acc1[r]);
            acc0[r] = fmaf(a.y, wb[1].x, acc0[r]); acc1[r] = fmaf(a.y, wb[1].y, acc1[r]);
            acc0[r] = fmaf(a.z, wb[2].x, acc0[r]); acc1[r] = fmaf(a.z, wb[2].y, acc1[r]);
            acc0[r] = fmaf(a.w, wb[3].x, acc0[r]); acc1[r] = fmaf(a.w, wb[3].y, acc1[r]);
        }
        if (e0 + 4 < 256) {
#pragma unroll
            for (int i = 0; i < 4; ++i) wb[i] = wn[i];
        }
    }

    float b0 = bias ? bias[2 * tid] : 0.f;
    float b1 = bias ? bias[2 * tid + 1] : 0.f;
#pragma unroll
    for (int r = 0; r < 16; ++r) {
        int row = row0 + r;
        if (row < M) {
            float2 o; o.x = acc0[r] + b0; o.y = acc1[r] + b1;
            *(float2*)&Out[(size_t)row * 512 + 2 * tid] = o;
        }
    }
}

// ---------------------------------------------------------------------------
// Kernel 2: per-cell blank/label log-probs via bf16 MFMA.
// Output in DIAGONAL-MAJOR float2 {blank, lab} layout: pairD[b][t+u][u].
// grid (25 t-tiles, 16 u-groups, 8 b), block (64,4): wave = one u, 16 t-rows.
// ---------------------------------------------------------------------------
__global__ __launch_bounds__(256) void k_cells(const float* __restrict__ f,
                                               const float* __restrict__ g,
                                               const unsigned short* __restrict__ Bfrag,
                                               const float* __restrict__ bp,
                                               const int* __restrict__ targets,
                                               const int* __restrict__ ilen,
                                               float2* __restrict__ pairD) {
    const int b = blockIdx.z;
    const int tlen = ilen[b];
    const int t0 = blockIdx.x * 16;
    if (t0 >= tlen) return;                       // block-uniform exit
    const int wave = threadIdx.y;
    const int lane = threadIdx.x;
    const int u_raw = blockIdx.y * 4 + wave;
    const int u = min(u_raw, 60);
    const int tid = wave * 64 + lane;

    __shared__ float fs[16 * 516];                // stride 516: 2-way bank alias (free)

    {   // stage f tile (16 rows x 512), coalesced float4, conflict-free writes
        const float4* src = (const float4*)(f + (size_t)(b * 400 + t0) * 512);
#pragma unroll
        for (int i = 0; i < 8; ++i) {
            int idx = tid + i * 256;              // float4 id, 0..2047
            int row = idx >> 7;
            int c4 = idx & 127;
            float4 v = src[idx];
            *(float4*)&fs[row * 516 + c4 * 4] = v;
        }
    }
    __syncthreads();

    const int quad = lane >> 4;
    const int m16 = lane & 15;
    const float* gu = g + (size_t)(b * 61 + u) * 512 + quad * 8;
    const float* fsrow = fs + m16 * 516 + quad * 8;
    f32x4 acc0 = {0.f, 0.f, 0.f, 0.f};
    f32x4 acc1 = {0.f, 0.f, 0.f, 0.f};

#pragma unroll 4
    for (int c = 0; c < 16; ++c) {
        float4 fa = *(const float4*)(fsrow + c * 32);
        float4 fb = *(const float4*)(fsrow + c * 32 + 4);
        float4 ga = *(const float4*)(gu + c * 32);
        float4 gb = *(const float4*)(gu + c * 32 + 4);
        union { unsigned short s[8]; bf16x8 v; } A;
        A.s[0] = f2bf(tanh_fast(fa.x + ga.x));
        A.s[1] = f2bf(tanh_fast(fa.y + ga.y));
        A.s[2] = f2bf(tanh_fast(fa.z + ga.z));
        A.s[3] = f2bf(tanh_fast(fa.w + ga.w));
        A.s[4] = f2bf(tanh_fast(fb.x + gb.x));
        A.s[5] = f2bf(tanh_fast(fb.y + gb.y));
        A.s[6] = f2bf(tanh_fast(fb.z + gb.z));
        A.s[7] = f2bf(tanh_fast(fb.w + gb.w));
        bf16x8 B0 = *(const bf16x8*)(Bfrag + ((size_t)(c * 2 + 0) * 64 + lane) * 8);
        bf16x8 B1 = *(const bf16x8*)(Bfrag + ((size_t)(c * 2 + 1) * 64 + lane) * 8);
        acc0 = __builtin_amdgcn_mfma_f32_16x16x32_bf16(A.v, B0, acc0, 0, 0, 0);
        acc1 = __builtin_amdgcn_mfma_f32_16x16x32_bf16(A.v, B1, acc1, 0, 0, 0);
    }

    // epilogue: D layout col n = lane&15, row m = quad*4 + reg
    float bp0 = bp[m16];
    int n1 = 16 + m16;
    bool n1v = (n1 < 28);
    float bp1 = n1v ? bp[n1] : 0.f;
    int tv = targets[b * 60 + min(u, 59)];

    float res_blank[4], res_lab[4];
#pragma unroll
    for (int r = 0; r < 4; ++r) {
        float l0 = acc0[r] + bp0;
        float l1 = n1v ? (acc1[r] + bp1) : NEGF;
        float mx = fmaxf(l0, l1);
        mx = fmaxf(mx, __shfl_xor(mx, 1, 64));
        mx = fmaxf(mx, __shfl_xor(mx, 2, 64));
        mx = fmaxf(mx, __shfl_xor(mx, 4, 64));
        mx = fmaxf(mx, __shfl_xor(mx, 8, 64));
        float s = __builtin_amdgcn_exp2f((l0 - mx) * LOG2E) +
                  __builtin_amdgcn_exp2f((l1 - mx) * LOG2E);
        s += __shfl_xor(s, 1, 64);
        s += __shfl_xor(s, 2, 64);
        s += __shfl_xor(s, 4, 64);
        s += __shfl_xor(s, 8, 64);
        float lse = mx + __logf(s);
        int base = lane & 48;
        float labsrc = (tv < 16) ? l0 : l1;
        float labv = __shfl(labsrc, base | (tv & 15), 64);
        float blankv = __shfl(l1, base | 11, 64);   // v=27 -> half1 local 11
        res_blank[r] = blankv - lse;
        res_lab[r] = labv - lse;
    }

    if (m16 == 0 && u_raw <= 60) {
        float2* Pd = pairD + (size_t)b * (DROWS_PAD * DPITCH);
#pragma unroll
        for (int r = 0; r < 4; ++r) {
            int t = t0 + quad * 4 + r;
            if (t < tlen) {
                int d = t + u;
                float2 pr;
                pr.x = res_blank[r];
                pr.y = (u <= 59) ? res_lab[r] : NEGF;
                Pd[d * DPITCH + u] = pr;
            }
        }
    }
}

// ---------------------------------------------------------------------------
// Kernel 3: anti-diagonal alpha recursion, one wave per batch.
// STATIC pipeline: fixed trip count, unconditional prefetch loads (padded
// buffer) so the compiler can emit counted s_waitcnt vmcnt(N) instead of
// draining vmcnt(0) every step. Answer captured in-loop at d == dstar.
// ---------------------------------------------------------------------------
__global__ __launch_bounds__(64) void k_alpha(const float2* __restrict__ pairD,
                                              const int* __restrict__ ilen,
                                              const int* __restrict__ ulenp,
                                              float* __restrict__ out) {
    const int b = blockIdx.x;
    const int u = threadIdx.x;
    const float2* Pd = pairD + (size_t)b * (DROWS_PAD * DPITCH);
    const int tl = ilen[b];
    const int ul = ulenp[b];
    const int dstar = tl - 1 + ul;
    const bool uok = (u <= 60);
    const bool lok = (u >= 1 && u <= 60);

    float cur = (u == 0) ? 0.f : NEGF;
    float saved = NEGF;

    float2 pf[PF];                       // raw loads; masks applied at consume
#pragma unroll
    for (int i = 0; i < PF; ++i) pf[i] = Pd[i * DPITCH + u];   // rows 0..PF-1

    for (int d0 = 1; d0 <= D_TRIP; d0 += PF) {
#pragma unroll
        for (int i = 0; i < PF; ++i) {
            const int d = d0 + i;
            float2 v = pf[i];
            pf[i] = Pd[(d + PF - 1) * DPITCH + u];   // UNCONDITIONAL prefetch
            int t = d - u;
            float bv = (t >= 1 && t <= 399 && uok) ? v.x : NEGF;
            float lvn = wave_shr1(v.y);              // lab[t][u-1] from lane u-1
            float lv = (lok && t >= 0 && t <= 399) ? lvn : NEGF;
            float up = wave_shr1(cur);
            float a = cur + bv;
            float c2 = up + lv;
            float mx = fmaxf(a, c2), mn = fminf(a, c2);
            float nv = mx + __logf(1.f + __builtin_amdgcn_exp2f((mn - mx) * LOG2E));
            bool valid = (t >= 0 && t <= 399 && uok);
            cur = valid ? nv : cur;
            saved = (d == dstar) ? cur : saved;      // capture answer row
        }
    }
    if (u == ul) out[b] = -(saved + Pd[dstar * DPITCH + u].x);
}

// ---------------------------------------------------------------------------
extern "C" void kernel_launch(void* const* d_in, const int* in_sizes, int n_in,
                              void* d_out, int out_size, void* d_ws, size_t ws_size,
                              hipStream_t stream) {
    const float* enc = (const float*)d_in[0];   // 8*400*256
    const float* dec = (const float*)d_in[1];   // 8*61*256
    const float* We  = (const float*)d_in[2];   // 256*512
    const float* Wd  = (const float*)d_in[3];   // 256*512
    const float* bf  = (const float*)d_in[4];   // 512
    const float* Wp  = (const float*)d_in[5];   // 512*28
    const float* bp  = (const float*)d_in[6];   // 28
    const int* targets = (const int*)d_in[7];   // 8*60
    const int* ilen    = (const int*)d_in[8];   // 8
    const int* ulen    = (const int*)d_in[9];   // 8
    float* out = (float*)d_out;                 // 8
    float* ws = (float*)d_ws;

    float* f     = ws;                                       // 1,638,400 floats
    float* g     = ws + 1638400;                             //   249,856 floats
    unsigned short* Bfrag = (unsigned short*)(ws + 1888256); // 16,384 u16 (8,192 floats)
    float2* pairD = (float2*)(ws + 1896448);                 // 8*480*64 float2 = 491,520 floats

    k_prep<<<232, 256, 0, stream>>>(enc, dec, We, Wd, bf, Wp, f, g, Bfrag);

    dim3 gridC(25, 16, 8);
    dim3 blockC(64, 4, 1);
    k_cells<<<gridC, blockC, 0, stream>>>(f, g, Bfrag, bp, targets, ilen, pairD);

    k_alpha<<<8, 64, 0, stream>>>(pairD, ilen, ulen, out);
}

// Round 5
// 158.785 us; speedup vs baseline: 4.6238x; 1.1951x over previous
//
#include <hip/hip_runtime.h>
#include <hip/hip_bf16.h>
#include <math.h>

#define NEGF (-1e30f)
#define LOG2E 1.4426950408889634f

typedef __attribute__((ext_vector_type(8))) short bf16x8;
typedef __attribute__((ext_vector_type(4))) float f32x4;

#define DROWS_PAD 480        // diagonals 0..459 used; padded to 480 for static prefetch
#define DPITCH 64            // lanes per diagonal row
#define D_TRIP 464           // fixed trip count: 29 * 16, >= max dstar (459)
#define PF 16                // prefetch depth (rows)

__device__ __forceinline__ float tanh_fast(float x) {
    // tanh(x) = 1 - 2/(exp(2x)+1)
    float e2 = __builtin_amdgcn_exp2f(x * 2.885390081777927f); // 2*log2(e)
    return fmaf(-2.f, __builtin_amdgcn_rcpf(e2 + 1.f), 1.f);
}

__device__ __forceinline__ unsigned short f2bf(float x) {
    __hip_bfloat16 h = __float2bfloat16(x);
    return *reinterpret_cast<unsigned short*>(&h);
}

__device__ __forceinline__ float wave_shr1(float x) {
    int i = __builtin_bit_cast(int, x);
    int r = __builtin_amdgcn_update_dpp(0, i, 0x138, 0xf, 0xf, true); // wf_shr:1
    return __builtin_bit_cast(float, r);
}

// ---------------------------------------------------------------------------
// Kernel 0 (pack): bf16 B-fragment packing for We (16384 entries), Wd (16384),
// Wp (2048). Entry layout (verified by k_cells since R2):
//   value[j] = W[kbase + j][n],  n = ntile*16 + (lane&15),
//   kbase = chunk*32 + ((lane>>4)&3)*8,  dst = Frag + entry*8.
// ---------------------------------------------------------------------------
__global__ __launch_bounds__(256) void k_pack(const float* __restrict__ We,
                                              const float* __restrict__ Wd,
                                              const float* __restrict__ Wp,
                                              unsigned short* __restrict__ WeFrag,
                                              unsigned short* __restrict__ WdFrag,
                                              unsigned short* __restrict__ BfragP) {
    int gid = blockIdx.x * 256 + threadIdx.x;
    if (gid < 32768) {   // We / Wd: s in [0,16384)
        const float* W = (gid < 16384) ? We : Wd;
        unsigned short* F = (gid < 16384) ? WeFrag : WdFrag;
        int s = gid & 16383;
        int lane = s & 63;
        int c = (s >> 6) & 7;
        int nt = s >> 9;                 // 0..31
        int n = nt * 16 + (lane & 15);
        int kbase = c * 32 + ((lane >> 4) & 3) * 8;
        unsigned short* dst = F + (size_t)s * 8;
#pragma unroll
        for (int j = 0; j < 8; ++j) dst[j] = f2bf(W[(size_t)(kbase + j) * 512 + n]);
    } else if (gid < 34816) {            // Wp: 2048 entries
        int s = gid - 32768;
        int lane = s & 63;
        int half = (s >> 6) & 1;
        int c = s >> 7;
        int n = half * 16 + (lane & 15);
        int kbase = c * 32 + (lane >> 4) * 8;
        unsigned short* dst = BfragP + (size_t)s * 8;
#pragma unroll
        for (int j = 0; j < 8; ++j) {
            float v = (n < 28) ? Wp[(kbase + j) * 28 + n] : 0.f;
            dst[j] = f2bf(v);
        }
    }
}

// ---------------------------------------------------------------------------
// Kernel 1 (MFMA projections): 1848 independent waves, 4 per block.
// Wave = 16 rows x 64 cols of f = enc@We (1600 waves) or g = dec@Wd + bf
// (248 waves). K=256 in 8 chunks; A-frag packed in-register from coalesced
// float4 loads; B-frags from packed L2-resident buffers. No LDS, no barriers.
// ---------------------------------------------------------------------------
__global__ __launch_bounds__(256) void k_gemm(const float* __restrict__ enc,
                                              const float* __restrict__ dec,
                                              const float* __restrict__ bfv,
                                              const unsigned short* __restrict__ WeFrag,
                                              const unsigned short* __restrict__ WdFrag,
                                              float* __restrict__ f,
                                              float* __restrict__ g) {
    const int wid = blockIdx.x * 4 + threadIdx.y;
    const int lane = threadIdx.x;
    const int m16 = lane & 15;
    const int quad = lane >> 4;

    const float* A; const unsigned short* WF; float* Out; int M, rt, ct; bool isg;
    if (wid < 1600) { A = enc; WF = WeFrag; Out = f; M = 3200; rt = wid >> 3; ct = wid & 7; isg = false; }
    else { int w2 = wid - 1600; A = dec; WF = WdFrag; Out = g; M = 488; rt = w2 >> 3; ct = w2 & 7; isg = true; }

    const int row = rt * 16 + m16;
    const float* arow = A + (size_t)min(row, M - 1) * 256 + quad * 8;

    f32x4 acc[4];
#pragma unroll
    for (int i = 0; i < 4; ++i) acc[i] = (f32x4){0.f, 0.f, 0.f, 0.f};

#pragma unroll
    for (int c = 0; c < 8; ++c) {
        float4 a0 = *(const float4*)(arow + c * 32);
        float4 a1 = *(const float4*)(arow + c * 32 + 4);
        union { unsigned short s[8]; bf16x8 v; } Af;
        Af.s[0] = f2bf(a0.x); Af.s[1] = f2bf(a0.y);
        Af.s[2] = f2bf(a0.z); Af.s[3] = f2bf(a0.w);
        Af.s[4] = f2bf(a1.x); Af.s[5] = f2bf(a1.y);
        Af.s[6] = f2bf(a1.z); Af.s[7] = f2bf(a1.w);
#pragma unroll
        for (int i = 0; i < 4; ++i) {
            int nt = ct * 4 + i;
            bf16x8 Bv = *(const bf16x8*)(WF + (size_t)((nt * 8 + c) * 64 + lane) * 8);
            acc[i] = __builtin_amdgcn_mfma_f32_16x16x32_bf16(Af.v, Bv, acc[i], 0, 0, 0);
        }
    }

#pragma unroll
    for (int i = 0; i < 4; ++i) {
        int n = ct * 64 + i * 16 + m16;
        float bv = isg ? bfv[n] : 0.f;
#pragma unroll
        for (int r = 0; r < 4; ++r) {
            int ro = rt * 16 + quad * 4 + r;
            if (ro < M) Out[(size_t)ro * 512 + n] = acc[i][r] + bv;
        }
    }
}

// ---------------------------------------------------------------------------
// Kernel 2: per-cell blank/label log-probs via bf16 MFMA.
// Output in DIAGONAL-MAJOR float2 {blank, lab} layout: pairD[b][t+u][u].
// grid (25 t-tiles, 16 u-groups, 8 b), block (64,4): wave = one u, 16 t-rows.
// ---------------------------------------------------------------------------
__global__ __launch_bounds__(256) void k_cells(const float* __restrict__ f,
                                               const float* __restrict__ g,
                                               const unsigned short* __restrict__ Bfrag,
                                               const float* __restrict__ bp,
                                               const int* __restrict__ targets,
                                               const int* __restrict__ ilen,
                                               float2* __restrict__ pairD) {
    const int b = blockIdx.z;
    const int tlen = ilen[b];
    const int t0 = blockIdx.x * 16;
    if (t0 >= tlen) return;                       // block-uniform exit
    const int wave = threadIdx.y;
    const int lane = threadIdx.x;
    const int u_raw = blockIdx.y * 4 + wave;
    const int u = min(u_raw, 60);
    const int tid = wave * 64 + lane;

    __shared__ float fs[16 * 516];                // stride 516: 2-way bank alias (free)

    {   // stage f tile (16 rows x 512), coalesced float4, conflict-free writes
        const float4* src = (const float4*)(f + (size_t)(b * 400 + t0) * 512);
#pragma unroll
        for (int i = 0; i < 8; ++i) {
            int idx = tid + i * 256;              // float4 id, 0..2047
            int row = idx >> 7;
            int c4 = idx & 127;
            float4 v = src[idx];
            *(float4*)&fs[row * 516 + c4 * 4] = v;
        }
    }
    __syncthreads();

    const int quad = lane >> 4;
    const int m16 = lane & 15;
    const float* gu = g + (size_t)(b * 61 + u) * 512 + quad * 8;
    const float* fsrow = fs + m16 * 516 + quad * 8;
    f32x4 acc0 = {0.f, 0.f, 0.f, 0.f};
    f32x4 acc1 = {0.f, 0.f, 0.f, 0.f};

#pragma unroll 4
    for (int c = 0; c < 16; ++c) {
        float4 fa = *(const float4*)(fsrow + c * 32);
        float4 fb = *(const float4*)(fsrow + c * 32 + 4);
        float4 ga = *(const float4*)(gu + c * 32);
        float4 gb = *(const float4*)(gu + c * 32 + 4);
        union { unsigned short s[8]; bf16x8 v; } A;
        A.s[0] = f2bf(tanh_fast(fa.x + ga.x));
        A.s[1] = f2bf(tanh_fast(fa.y + ga.y));
        A.s[2] = f2bf(tanh_fast(fa.z + ga.z));
        A.s[3] = f2bf(tanh_fast(fa.w + ga.w));
        A.s[4] = f2bf(tanh_fast(fb.x + gb.x));
        A.s[5] = f2bf(tanh_fast(fb.y + gb.y));
        A.s[6] = f2bf(tanh_fast(fb.z + gb.z));
        A.s[7] = f2bf(tanh_fast(fb.w + gb.w));
        bf16x8 B0 = *(const bf16x8*)(Bfrag + ((size_t)(c * 2 + 0) * 64 + lane) * 8);
        bf16x8 B1 = *(const bf16x8*)(Bfrag + ((size_t)(c * 2 + 1) * 64 + lane) * 8);
        acc0 = __builtin_amdgcn_mfma_f32_16x16x32_bf16(A.v, B0, acc0, 0, 0, 0);
        acc1 = __builtin_amdgcn_mfma_f32_16x16x32_bf16(A.v, B1, acc1, 0, 0, 0);
    }

    // epilogue: D layout col n = lane&15, row m = quad*4 + reg
    float bp0 = bp[m16];
    int n1 = 16 + m16;
    bool n1v = (n1 < 28);
    float bp1 = n1v ? bp[n1] : 0.f;
    int tv = targets[b * 60 + min(u, 59)];

    float res_blank[4], res_lab[4];
#pragma unroll
    for (int r = 0; r < 4; ++r) {
        float l0 = acc0[r] + bp0;
        float l1 = n1v ? (acc1[r] + bp1) : NEGF;
        float mx = fmaxf(l0, l1);
        mx = fmaxf(mx, __shfl_xor(mx, 1, 64));
        mx = fmaxf(mx, __shfl_xor(mx, 2, 64));
        mx = fmaxf(mx, __shfl_xor(mx, 4, 64));
        mx = fmaxf(mx, __shfl_xor(mx, 8, 64));
        float s = __builtin_amdgcn_exp2f((l0 - mx) * LOG2E) +
                  __builtin_amdgcn_exp2f((l1 - mx) * LOG2E);
        s += __shfl_xor(s, 1, 64);
        s += __shfl_xor(s, 2, 64);
        s += __shfl_xor(s, 4, 64);
        s += __shfl_xor(s, 8, 64);
        float lse = mx + __logf(s);
        int base = lane & 48;
        float labsrc = (tv < 16) ? l0 : l1;
        float labv = __shfl(labsrc, base | (tv & 15), 64);
        float blankv = __shfl(l1, base | 11, 64);   // v=27 -> half1 local 11
        res_blank[r] = blankv - lse;
        res_lab[r] = labv - lse;
    }

    if (m16 == 0 && u_raw <= 60) {
        float2* Pd = pairD + (size_t)b * (DROWS_PAD * DPITCH);
#pragma unroll
        for (int r = 0; r < 4; ++r) {
            int t = t0 + quad * 4 + r;
            if (t < tlen) {
                int d = t + u;
                float2 pr;
                pr.x = res_blank[r];
                pr.y = (u <= 59) ? res_lab[r] : NEGF;
                Pd[d * DPITCH + u] = pr;
            }
        }
    }
}

// ---------------------------------------------------------------------------
// Kernel 3: anti-diagonal alpha recursion, one wave per batch.
// STATIC pipeline: fixed trip count, unconditional prefetch loads (padded
// buffer) so the compiler emits counted s_waitcnt vmcnt(N).
// ---------------------------------------------------------------------------
__global__ __launch_bounds__(64) void k_alpha(const float2* __restrict__ pairD,
                                              const int* __restrict__ ilen,
                                              const int* __restrict__ ulenp,
                                              float* __restrict__ out) {
    const int b = blockIdx.x;
    const int u = threadIdx.x;
    const float2* Pd = pairD + (size_t)b * (DROWS_PAD * DPITCH);
    const int tl = ilen[b];
    const int ul = ulenp[b];
    const int dstar = tl - 1 + ul;
    const bool uok = (u <= 60);
    const bool lok = (u >= 1 && u <= 60);

    float cur = (u == 0) ? 0.f : NEGF;
    float saved = NEGF;

    float2 pf[PF];                       // raw loads; masks applied at consume
#pragma unroll
    for (int i = 0; i < PF; ++i) pf[i] = Pd[i * DPITCH + u];   // rows 0..PF-1

    for (int d0 = 1; d0 <= D_TRIP; d0 += PF) {
#pragma unroll
        for (int i = 0; i < PF; ++i) {
            const int d = d0 + i;
            float2 v = pf[i];
            pf[i] = Pd[(d + PF - 1) * DPITCH + u];   // UNCONDITIONAL prefetch
            int t = d - u;
            float bv = (t >= 1 && t <= 399 && uok) ? v.x : NEGF;
            float lvn = wave_shr1(v.y);              // lab[t][u-1] from lane u-1
            float lv = (lok && t >= 0 && t <= 399) ? lvn : NEGF;
            float up = wave_shr1(cur);
            float a = cur + bv;
            float c2 = up + lv;
            float mx = fmaxf(a, c2), mn = fminf(a, c2);
            float nv = mx + __logf(1.f + __builtin_amdgcn_exp2f((mn - mx) * LOG2E));
            bool valid = (t >= 0 && t <= 399 && uok);
            cur = valid ? nv : cur;
            saved = (d == dstar) ? cur : saved;      // capture answer row
        }
    }
    if (u == ul) out[b] = -(saved + Pd[dstar * DPITCH + u].x);
}

// ---------------------------------------------------------------------------
extern "C" void kernel_launch(void* const* d_in, const int* in_sizes, int n_in,
                              void* d_out, int out_size, void* d_ws, size_t ws_size,
                              hipStream_t stream) {
    const float* enc = (const float*)d_in[0];   // 8*400*256
    const float* dec = (const float*)d_in[1];   // 8*61*256
    const float* We  = (const float*)d_in[2];   // 256*512
    const float* Wd  = (const float*)d_in[3];   // 256*512
    const float* bf  = (const float*)d_in[4];   // 512
    const float* Wp  = (const float*)d_in[5];   // 512*28
    const float* bp  = (const float*)d_in[6];   // 28
    const int* targets = (const int*)d_in[7];   // 8*60
    const int* ilen    = (const int*)d_in[8];   // 8
    const int* ulen    = (const int*)d_in[9];   // 8
    float* out = (float*)d_out;                 // 8
    float* ws = (float*)d_ws;

    float* f     = ws;                                        // 1,638,400 floats
    float* g     = ws + 1638400;                              //   249,856 floats
    unsigned short* BfragP = (unsigned short*)(ws + 1888256); //  16,384 u16 ( 8,192 floats)
    unsigned short* WeFrag = (unsigned short*)(ws + 1896448); // 131,072 u16 (65,536 floats)
    unsigned short* WdFrag = (unsigned short*)(ws + 1961984); // 131,072 u16 (65,536 floats)
    float2* pairD = (float2*)(ws + 2027520);                  // 8*480*64 float2 (491,520 floats)

    k_pack<<<136, 256, 0, stream>>>(We, Wd, Wp, WeFrag, WdFrag, BfragP);

    k_gemm<<<462, dim3(64, 4, 1), 0, stream>>>(enc, dec, bf, WeFrag, WdFrag, f, g);

    dim3 gridC(25, 16, 8);
    dim3 blockC(64, 4, 1);
    k_cells<<<gridC, blockC, 0, stream>>>(f, g, BfragP, bp, targets, ilen, pairD);

    k_alpha<<<8, 64, 0, stream>>>(pairD, ilen, ulen, out);
}

// Round 6
// 158.261 us; speedup vs baseline: 4.6391x; 1.0033x over previous
//
#include <hip/hip_runtime.h>
#include <hip/hip_bf16.h>
#include <math.h>

#define NEGF (-1e30f)
#define LOG2E 1.4426950408889634f
#define TSCALE 2.885390081777927f     // 2*log2(e), folded into f and g

typedef __attribute__((ext_vector_type(8))) short bf16x8;
typedef __attribute__((ext_vector_type(4))) float f32x4;

#define DROWS_PAD 480        // diagonals 0..459 used; padded for static prefetch
#define DPITCH 64
#define PF 16                // prefetch depth (rows)

__device__ __forceinline__ unsigned short f2bf(float x) {
    __hip_bfloat16 h = __float2bfloat16(x);
    return *reinterpret_cast<unsigned short*>(&h);
}

__device__ __forceinline__ float wave_shr1(float x) {
    int i = __builtin_bit_cast(int, x);
    int r = __builtin_amdgcn_update_dpp(0, i, 0x138, 0xf, 0xf, true); // wf_shr:1
    return __builtin_bit_cast(float, r);
}

// reciprocal via bit-hack + 1 Newton step: pure VALU (no trans pipe).
// d >= 1 always here; rel err ~0.25% after NR, below bf16 ulp.
__device__ __forceinline__ float4 rcp4_nr(float4 d) {
    float4 y;
    y.x = __builtin_bit_cast(float, 0x7EF311C3 - __builtin_bit_cast(int, d.x));
    y.y = __builtin_bit_cast(float, 0x7EF311C3 - __builtin_bit_cast(int, d.y));
    y.z = __builtin_bit_cast(float, 0x7EF311C3 - __builtin_bit_cast(int, d.z));
    y.w = __builtin_bit_cast(float, 0x7EF311C3 - __builtin_bit_cast(int, d.w));
    float4 t;                                   // t = 2 - d*y  (pk fma)
    t.x = fmaf(-d.x, y.x, 2.f); t.y = fmaf(-d.y, y.y, 2.f);
    t.z = fmaf(-d.z, y.z, 2.f); t.w = fmaf(-d.w, y.w, 2.f);
    y.x *= t.x; y.y *= t.y; y.z *= t.z; y.w *= t.w;
    return y;
}

// ---------------------------------------------------------------------------
// Kernel 0 (pack): bf16 B-fragments for We (16384 entries), Wd (16384),
// and -2*Wp (2048, sigmoid form); plus csbp[v] = colsum(Wp)[v] + bp[v].
// ---------------------------------------------------------------------------
__global__ __launch_bounds__(256) void k_pack(const float* __restrict__ We,
                                              const float* __restrict__ Wd,
                                              const float* __restrict__ Wp,
                                              const float* __restrict__ bp,
                                              unsigned short* __restrict__ WeFrag,
                                              unsigned short* __restrict__ WdFrag,
                                              unsigned short* __restrict__ BfragP,
                                              float* __restrict__ csbp) {
    int gid = blockIdx.x * 256 + threadIdx.x;
    if (gid < 32768) {   // We / Wd
        const float* W = (gid < 16384) ? We : Wd;
        unsigned short* F = (gid < 16384) ? WeFrag : WdFrag;
        int s = gid & 16383;
        int lane = s & 63;
        int c = (s >> 6) & 7;
        int nt = s >> 9;
        int n = nt * 16 + (lane & 15);
        int kbase = c * 32 + ((lane >> 4) & 3) * 8;
        unsigned short* dst = F + (size_t)s * 8;
#pragma unroll
        for (int j = 0; j < 8; ++j) dst[j] = f2bf(W[(size_t)(kbase + j) * 512 + n]);
    } else if (gid < 34816) {            // -2*Wp: 2048 entries
        int s = gid - 32768;
        int lane = s & 63;
        int half = (s >> 6) & 1;
        int c = s >> 7;
        int n = half * 16 + (lane & 15);
        int kbase = c * 32 + (lane >> 4) * 8;
        unsigned short* dst = BfragP + (size_t)s * 8;
#pragma unroll
        for (int j = 0; j < 8; ++j) {
            float v = (n < 28) ? (-2.f * Wp[(kbase + j) * 28 + n]) : 0.f;
            dst[j] = f2bf(v);
        }
    } else if (gid < 34848) {            // csbp: 32 entries
        int v = gid - 34816;
        float s = 0.f;
        if (v < 28) {
            for (int k = 0; k < 512; ++k) s += Wp[k * 28 + v];
            s += bp[v];
        }
        csbp[v] = s;
    }
}

// ---------------------------------------------------------------------------
// Kernel 1 (MFMA projections): f = (enc@We)*TSCALE, g = (dec@Wd + bf)*TSCALE.
// 1848 independent waves, 4/block; no LDS, no barriers.
// ---------------------------------------------------------------------------
__global__ __launch_bounds__(256) void k_gemm(const float* __restrict__ enc,
                                              const float* __restrict__ dec,
                                              const float* __restrict__ bfv,
                                              const unsigned short* __restrict__ WeFrag,
                                              const unsigned short* __restrict__ WdFrag,
                                              float* __restrict__ f,
                                              float* __restrict__ g) {
    const int wid = blockIdx.x * 4 + threadIdx.y;
    const int lane = threadIdx.x;
    const int m16 = lane & 15;
    const int quad = lane >> 4;

    const float* A; const unsigned short* WF; float* Out; int M, rt, ct; bool isg;
    if (wid < 1600) { A = enc; WF = WeFrag; Out = f; M = 3200; rt = wid >> 3; ct = wid & 7; isg = false; }
    else { int w2 = wid - 1600; A = dec; WF = WdFrag; Out = g; M = 488; rt = w2 >> 3; ct = w2 & 7; isg = true; }

    const int row = rt * 16 + m16;
    const float* arow = A + (size_t)min(row, M - 1) * 256 + quad * 8;

    f32x4 acc[4];
#pragma unroll
    for (int i = 0; i < 4; ++i) acc[i] = (f32x4){0.f, 0.f, 0.f, 0.f};

#pragma unroll
    for (int c = 0; c < 8; ++c) {
        float4 a0 = *(const float4*)(arow + c * 32);
        float4 a1 = *(const float4*)(arow + c * 32 + 4);
        union { unsigned short s[8]; bf16x8 v; } Af;
        Af.s[0] = f2bf(a0.x); Af.s[1] = f2bf(a0.y);
        Af.s[2] = f2bf(a0.z); Af.s[3] = f2bf(a0.w);
        Af.s[4] = f2bf(a1.x); Af.s[5] = f2bf(a1.y);
        Af.s[6] = f2bf(a1.z); Af.s[7] = f2bf(a1.w);
#pragma unroll
        for (int i = 0; i < 4; ++i) {
            int nt = ct * 4 + i;
            bf16x8 Bv = *(const bf16x8*)(WF + (size_t)((nt * 8 + c) * 64 + lane) * 8);
            acc[i] = __builtin_amdgcn_mfma_f32_16x16x32_bf16(Af.v, Bv, acc[i], 0, 0, 0);
        }
    }

#pragma unroll
    for (int i = 0; i < 4; ++i) {
        int n = ct * 64 + i * 16 + m16;
        float bv = isg ? bfv[n] : 0.f;
#pragma unroll
        for (int r = 0; r < 4; ++r) {
            int ro = rt * 16 + quad * 4 + r;
            if (ro < M) Out[(size_t)ro * 512 + n] = (acc[i][r] + bv) * TSCALE;
        }
    }
}

// ---------------------------------------------------------------------------
// Kernel 2: per-cell blank/label log-probs.
// sigma = 1/(1+exp2(f+g)) fed to MFMA against B = -2*Wp; logits = csbp + acc.
// Skips t-tiles >= ilen[b] and u-tiles > ulen[b] (dead for the answer cell).
// ---------------------------------------------------------------------------
__global__ __launch_bounds__(256) void k_cells(const float* __restrict__ f,
                                               const float* __restrict__ g,
                                               const unsigned short* __restrict__ Bfrag,
                                               const float* __restrict__ csbp,
                                               const int* __restrict__ targets,
                                               const int* __restrict__ ilen,
                                               const int* __restrict__ ulenp,
                                               float2* __restrict__ pairD) {
    const int b = blockIdx.z;
    const int tlen = ilen[b];
    const int t0 = blockIdx.x * 16;
    if (t0 >= tlen) return;                       // block-uniform exit
    if ((int)blockIdx.y * 4 > ulenp[b]) return;   // u > ulen never feeds answer
    const int wave = threadIdx.y;
    const int lane = threadIdx.x;
    const int u_raw = blockIdx.y * 4 + wave;
    const int u = min(u_raw, 60);
    const int tid = wave * 64 + lane;

    __shared__ float fs[16 * 516];                // stride 516: 2-way alias (free)

    {   // stage f tile (16 rows x 512), coalesced float4, conflict-free writes
        const float4* src = (const float4*)(f + (size_t)(b * 400 + t0) * 512);
#pragma unroll
        for (int i = 0; i < 8; ++i) {
            int idx = tid + i * 256;
            int row = idx >> 7;
            int c4 = idx & 127;
            float4 v = src[idx];
            *(float4*)&fs[row * 516 + c4 * 4] = v;
        }
    }
    __syncthreads();

    const int quad = lane >> 4;
    const int m16 = lane & 15;
    const float* gu = g + (size_t)(b * 61 + u) * 512 + quad * 8;
    const float* fsrow = fs + m16 * 516 + quad * 8;
    f32x4 acc0 = {0.f, 0.f, 0.f, 0.f};
    f32x4 acc1 = {0.f, 0.f, 0.f, 0.f};
    const float4 one4 = make_float4(1.f, 1.f, 1.f, 1.f);

#pragma unroll 4
    for (int c = 0; c < 16; ++c) {
        float4 fa = *(const float4*)(fsrow + c * 32);
        float4 fb = *(const float4*)(fsrow + c * 32 + 4);
        float4 ga = *(const float4*)(gu + c * 32);
        float4 gb = *(const float4*)(gu + c * 32 + 4);
        float4 s0 = fa + ga;                      // pk adds (pre-scaled by 2log2e)
        float4 s1 = fb + gb;
        float4 e0, e1;
        e0.x = __builtin_amdgcn_exp2f(s0.x); e0.y = __builtin_amdgcn_exp2f(s0.y);
        e0.z = __builtin_amdgcn_exp2f(s0.z); e0.w = __builtin_amdgcn_exp2f(s0.w);
        e1.x = __builtin_amdgcn_exp2f(s1.x); e1.y = __builtin_amdgcn_exp2f(s1.y);
        e1.z = __builtin_amdgcn_exp2f(s1.z); e1.w = __builtin_amdgcn_exp2f(s1.w);
        float4 r0 = rcp4_nr(e0 + one4);           // sigma = 1/(1+e), no trans rcp
        float4 r1 = rcp4_nr(e1 + one4);
        union { unsigned short s[8]; bf16x8 v; } A;
        A.s[0] = f2bf(r0.x); A.s[1] = f2bf(r0.y);
        A.s[2] = f2bf(r0.z); A.s[3] = f2bf(r0.w);
        A.s[4] = f2bf(r1.x); A.s[5] = f2bf(r1.y);
        A.s[6] = f2bf(r1.z); A.s[7] = f2bf(r1.w);
        bf16x8 B0 = *(const bf16x8*)(Bfrag + ((size_t)(c * 2 + 0) * 64 + lane) * 8);
        bf16x8 B1 = *(const bf16x8*)(Bfrag + ((size_t)(c * 2 + 1) * 64 + lane) * 8);
        acc0 = __builtin_amdgcn_mfma_f32_16x16x32_bf16(A.v, B0, acc0, 0, 0, 0);
        acc1 = __builtin_amdgcn_mfma_f32_16x16x32_bf16(A.v, B1, acc1, 0, 0, 0);
    }

    // epilogue: logits l[v] = csbp[v] + acc  (acc = sum(-2Wp * sigma))
    float cs0 = csbp[m16];
    int n1 = 16 + m16;
    bool n1v = (n1 < 28);
    float cs1 = csbp[n1 & 31];
    int tv = targets[b * 60 + min(u, 59)];

    float res_blank[4], res_lab[4];
#pragma unroll
    for (int r = 0; r < 4; ++r) {
        float l0 = acc0[r] + cs0;
        float l1 = n1v ? (acc1[r] + cs1) : NEGF;
        float mx = fmaxf(l0, l1);
        mx = fmaxf(mx, __shfl_xor(mx, 1, 64));
        mx = fmaxf(mx, __shfl_xor(mx, 2, 64));
        mx = fmaxf(mx, __shfl_xor(mx, 4, 64));
        mx = fmaxf(mx, __shfl_xor(mx, 8, 64));
        float s = __builtin_amdgcn_exp2f((l0 - mx) * LOG2E) +
                  __builtin_amdgcn_exp2f((l1 - mx) * LOG2E);
        s += __shfl_xor(s, 1, 64);
        s += __shfl_xor(s, 2, 64);
        s += __shfl_xor(s, 4, 64);
        s += __shfl_xor(s, 8, 64);
        float lse = mx + __logf(s);
        int base = lane & 48;
        float labsrc = (tv < 16) ? l0 : l1;
        float labv = __shfl(labsrc, base | (tv & 15), 64);
        float blankv = __shfl(l1, base | 11, 64);   // v=27 -> half1 local 11
        res_blank[r] = blankv - lse;
        res_lab[r] = labv - lse;
    }

    if (m16 == 0 && u_raw <= 60) {
        float2* Pd = pairD + (size_t)b * (DROWS_PAD * DPITCH);
#pragma unroll
        for (int r = 0; r < 4; ++r) {
            int t = t0 + quad * 4 + r;
            if (t < tlen) {
                int d = t + u;
                float2 pr;
                pr.x = res_blank[r];
                pr.y = (u <= 59) ? res_lab[r] : NEGF;
                Pd[d * DPITCH + u] = pr;
            }
        }
    }
}

// ---------------------------------------------------------------------------
// Kernel 3: anti-diagonal alpha recursion, one wave per batch.
// Static pipeline (unconditional prefetch); per-batch wave-uniform trip count.
// ---------------------------------------------------------------------------
__global__ __launch_bounds__(64) void k_alpha(const float2* __restrict__ pairD,
                                              const int* __restrict__ ilen,
                                              const int* __restrict__ ulenp,
                                              float* __restrict__ out) {
    const int b = blockIdx.x;
    const int u = threadIdx.x;
    const float2* Pd = pairD + (size_t)b * (DROWS_PAD * DPITCH);
    const int tl = ilen[b];
    const int ul = ulenp[b];
    const int dstar = tl - 1 + ul;
    const int dmax = ((dstar + PF - 1) / PF) * PF;   // uniform; <= 464
    const bool uok = (u <= 60);
    const bool lok = (u >= 1 && u <= 60);

    float cur = (u == 0) ? 0.f : NEGF;
    float saved = NEGF;

    float2 pf[PF];
#pragma unroll
    for (int i = 0; i < PF; ++i) pf[i] = Pd[i * DPITCH + u];

    for (int d0 = 1; d0 <= dmax; d0 += PF) {
#pragma unroll
        for (int i = 0; i < PF; ++i) {
            const int d = d0 + i;
            float2 v = pf[i];
            pf[i] = Pd[(d + PF - 1) * DPITCH + u];   // unconditional prefetch (<480)
            int t = d - u;
            float bv = (t >= 1 && t <= 399 && uok) ? v.x : NEGF;
            float lvn = wave_shr1(v.y);
            float lv = (lok && t >= 0 && t <= 399) ? lvn : NEGF;
            float up = wave_shr1(cur);
            float a = cur + bv;
            float c2 = up + lv;
            float mx = fmaxf(a, c2), mn = fminf(a, c2);
            float nv = mx + __logf(1.f + __builtin_amdgcn_exp2f((mn - mx) * LOG2E));
            bool valid = (t >= 0 && t <= 399 && uok);
            cur = valid ? nv : cur;
            saved = (d == dstar) ? cur : saved;
        }
    }
    if (u == ul) out[b] = -(saved + Pd[dstar * DPITCH + u].x);
}

// ---------------------------------------------------------------------------
extern "C" void kernel_launch(void* const* d_in, const int* in_sizes, int n_in,
                              void* d_out, int out_size, void* d_ws, size_t ws_size,
                              hipStream_t stream) {
    const float* enc = (const float*)d_in[0];
    const float* dec = (const float*)d_in[1];
    const float* We  = (const float*)d_in[2];
    const float* Wd  = (const float*)d_in[3];
    const float* bf  = (const float*)d_in[4];
    const float* Wp  = (const float*)d_in[5];
    const float* bp  = (const float*)d_in[6];
    const int* targets = (const int*)d_in[7];
    const int* ilen    = (const int*)d_in[8];
    const int* ulen    = (const int*)d_in[9];
    float* out = (float*)d_out;
    float* ws = (float*)d_ws;

    float* f     = ws;                                        // 1,638,400 f
    float* g     = ws + 1638400;                              //   249,856 f
    unsigned short* BfragP = (unsigned short*)(ws + 1888256); //  16,384 u16
    unsigned short* WeFrag = (unsigned short*)(ws + 1896448); // 131,072 u16
    unsigned short* WdFrag = (unsigned short*)(ws + 1961984); // 131,072 u16
    float* csbp  = ws + 2027520;                              //        32 f
    float2* pairD = (float2*)(ws + 2027552);                  // 8*480*64 float2

    k_pack<<<137, 256, 0, stream>>>(We, Wd, Wp, bp, WeFrag, WdFrag, BfragP, csbp);

    k_gemm<<<462, dim3(64, 4, 1), 0, stream>>>(enc, dec, bf, WeFrag, WdFrag, f, g);

    dim3 gridC(25, 16, 8);
    dim3 blockC(64, 4, 1);
    k_cells<<<gridC, blockC, 0, stream>>>(f, g, BfragP, csbp, targets, ilen, ulen, pairD);

    k_alpha<<<8, 64, 0, stream>>>(pairD, ilen, ulen, out);
}